// Round 12
// baseline (515.439 us; speedup 1.0000x reference)
//
#include <hip/hip_runtime.h>
#include <math.h>

#define T_LEN 1024
#define C_DIM 2048
#define H_N   32
#define HEAD  64
#define BTC   (T_LEN * C_DIM)
#define REC4  1600  // floats per (t-quad,h): [DD|A1-4|B1-4|R1-4|C1-4]x64 + vq[256] + oc[256]
#define RKV_N 6144
#define NQ    (T_LEN / 4)   // 256 quad-steps

typedef __attribute__((ext_vector_type(8))) __bf16 bf16x8;
typedef __attribute__((ext_vector_type(4))) float  f32x4;

// ---------------- async global->LDS helper (16B/lane, wave-uniform LDS base) -------------
__device__ __forceinline__ void gll16(const void* g, void* l) {
    __builtin_amdgcn_global_load_lds((const __attribute__((address_space(1))) void*)g,
                                     (__attribute__((address_space(3))) void*)l, 16, 0, 0);
}

// 16-lane reduce, pure DPP
__device__ __forceinline__ float hex_add(float x) {
    int a = __builtin_amdgcn_mov_dpp(__float_as_int(x), 0xB1, 0xF, 0xF, true);   // quad_perm [1,0,3,2]
    float y = x + __int_as_float(a);
    int b = __builtin_amdgcn_mov_dpp(__float_as_int(y), 0x4E, 0xF, 0xF, true);   // quad_perm [2,3,0,1]
    float z = y + __int_as_float(b);
    int c = __builtin_amdgcn_mov_dpp(__float_as_int(z), 0x141, 0xF, 0xF, true);  // row_half_mirror
    float w = z + __int_as_float(c);
    int d = __builtin_amdgcn_mov_dpp(__float_as_int(w), 0x140, 0xF, 0xF, true);  // row_mirror
    return w + __int_as_float(d);
}

// broadcast float4 from src lane (4x ds_bpermute, compiler-visible)
__device__ __forceinline__ float4 shfl4(float4 v, int src) {
    float4 o;
    o.x = __shfl(v.x, src);
    o.y = __shfl(v.y, src);
    o.z = __shfl(v.z, src);
    o.w = __shfl(v.w, src);
    return o;
}

// ---------------- cast x -> bf16 ----------------
__global__ void cast_bf16_k(const float* __restrict__ s, __bf16* __restrict__ d, int n) {
    int i = blockIdx.x * 256 + threadIdx.x;
    if (i < n) d[i] = (__bf16)s[i];
}

// ---------------- fused LoRA-1 activation ----------------
__global__ void act_lora1_k(const float* __restrict__ s, __bf16* __restrict__ d) {
    int i = blockIdx.x * 256 + threadIdx.x;
    float v = s[i];
    if ((i & 255) < 96) v = tanhf(v);
    d[i] = (__bf16)v;
}

// ---------------- batched transpose + cast ------------
struct TransBatch {
    const float* s[10];
    __bf16*      d[10];
    int R[10];
    int C[10];
};
__global__ void transpose_batch_k(TransBatch tb) {
    int z = blockIdx.z;
    const float* src = tb.s[z];
    __bf16* dst = tb.d[z];
    int R = tb.R[z], C = tb.C[z];
    int c0 = blockIdx.x * 32, r0 = blockIdx.y * 32;
    if (c0 >= C || r0 >= R) return;
    __shared__ float tile[32][33];
    int tx = threadIdx.x, ty = threadIdx.y;
#pragma unroll
    for (int i = 0; i < 32; i += 8)
        tile[ty + i][tx] = src[(size_t)(r0 + ty + i) * C + c0 + tx];
    __syncthreads();
#pragma unroll
    for (int i = 0; i < 32; i += 8)
        dst[(size_t)(c0 + ty + i) * R + r0 + tx] = (__bf16)tile[tx][ty + i];
}

// ---------------- GEMM 64x128 tile ----------------
__global__ __launch_bounds__(256) void gemm_lds_64x128(
    const __bf16* __restrict__ A, const __bf16* __restrict__ BT,
    float* __restrict__ O, int M, int N, int K) {
    __shared__ __bf16 As[64 * 32];
    __shared__ __bf16 Bs[128 * 32];
    int tid  = threadIdx.x;
    int lane = tid & 63;
    int wv   = tid >> 6;
    int m    = lane & 15;
    int q    = lane >> 4;
    int wr   = wv >> 1, wc = wv & 1;
    int row0 = blockIdx.x * 64;
    int col0 = blockIdx.y * 128;

    int srow  = tid >> 2;
    int skoff = (tid & 3) * 8;
    const __bf16* agp = A  + (size_t)(row0 + srow) * K + skoff;
    const __bf16* bgp = BT + (size_t)(col0 + srow) * K + skoff;
    __bf16* alp = As + (size_t)(tid & ~63) * 8;
    __bf16* blp = Bs + (size_t)(tid & ~63) * 8;

    f32x4 acc[2][4];
#pragma unroll
    for (int i = 0; i < 2; i++)
#pragma unroll
        for (int j = 0; j < 4; j++) acc[i][j] = {0.f, 0.f, 0.f, 0.f};

    for (int k0 = 0; k0 < K; k0 += 32) {
        gll16(agp + k0, alp);
        gll16(bgp + k0, blp);
        gll16(bgp + (size_t)64 * K + k0, blp + 64 * 32);
        __syncthreads();

        bf16x8 af[2], bfv[4];
#pragma unroll
        for (int i = 0; i < 2; i++)
            af[i] = *(const bf16x8*)&As[(wr * 32 + i * 16 + m) * 32 + q * 8];
#pragma unroll
        for (int j = 0; j < 4; j++)
            bfv[j] = *(const bf16x8*)&Bs[(wc * 64 + j * 16 + m) * 32 + q * 8];
#pragma unroll
        for (int i = 0; i < 2; i++)
#pragma unroll
            for (int j = 0; j < 4; j++)
                acc[i][j] = __builtin_amdgcn_mfma_f32_16x16x32_bf16(af[i], bfv[j], acc[i][j], 0, 0, 0);
        __syncthreads();
    }

#pragma unroll
    for (int i = 0; i < 2; i++) {
        int orow = row0 + wr * 32 + i * 16 + q * 4;
#pragma unroll
        for (int j = 0; j < 4; j++) {
            int ocol = col0 + wc * 64 + j * 16 + m;
#pragma unroll
            for (int t = 0; t < 4; t++)
                O[(size_t)(orow + t) * N + ocol] = acc[i][j][t];
        }
    }
}

// ---------------- GEMM 128x128 tile (big rkv GEMM) ----------------
__global__ __launch_bounds__(256) void gemm_lds_128x128(
    const __bf16* __restrict__ A, const __bf16* __restrict__ BT,
    float* __restrict__ O, int M, int N, int K) {
    __shared__ __bf16 As[128 * 32];
    __shared__ __bf16 Bs[128 * 32];
    int tid  = threadIdx.x;
    int lane = tid & 63;
    int wv   = tid >> 6;
    int m    = lane & 15;
    int q    = lane >> 4;
    int row0 = blockIdx.x * 128;
    int col0 = blockIdx.y * 128;

    int srow  = tid >> 2;
    int skoff = (tid & 3) * 8;
    const __bf16* agp = A  + (size_t)(row0 + srow) * K + skoff;
    const __bf16* bgp = BT + (size_t)(col0 + srow) * K + skoff;
    __bf16* alp = As + (size_t)(tid & ~63) * 8;
    __bf16* blp = Bs + (size_t)(tid & ~63) * 8;

    f32x4 acc[2][8];
#pragma unroll
    for (int i = 0; i < 2; i++)
#pragma unroll
        for (int j = 0; j < 8; j++) acc[i][j] = {0.f, 0.f, 0.f, 0.f};

    for (int k0 = 0; k0 < K; k0 += 32) {
        gll16(agp + k0, alp);
        gll16(agp + (size_t)64 * K + k0, alp + 64 * 32);
        gll16(bgp + k0, blp);
        gll16(bgp + (size_t)64 * K + k0, blp + 64 * 32);
        __syncthreads();

        bf16x8 af[2], bfv[8];
#pragma unroll
        for (int i = 0; i < 2; i++)
            af[i] = *(const bf16x8*)&As[(wv * 32 + i * 16 + m) * 32 + q * 8];
#pragma unroll
        for (int j = 0; j < 8; j++)
            bfv[j] = *(const bf16x8*)&Bs[(j * 16 + m) * 32 + q * 8];
#pragma unroll
        for (int i = 0; i < 2; i++)
#pragma unroll
            for (int j = 0; j < 8; j++)
                acc[i][j] = __builtin_amdgcn_mfma_f32_16x16x32_bf16(af[i], bfv[j], acc[i][j], 0, 0, 0);
        __syncthreads();
    }

#pragma unroll
    for (int i = 0; i < 2; i++) {
        int orow = row0 + wv * 32 + i * 16 + q * 4;
#pragma unroll
        for (int j = 0; j < 8; j++) {
            int ocol = col0 + j * 16 + m;
#pragma unroll
            for (int t = 0; t < 4; t++)
                O[(size_t)(orow + t) * N + ocol] = acc[i][j][t];
        }
    }
}

// ---------------- fused LoRA-2 GEMM (grid.z = 3) ----------------
struct Lora2Cfg {
    const __bf16* A[3];
    const __bf16* BT[3];
    float*        O[3];
    int K[3];
};
__global__ __launch_bounds__(256) void gemm_lora2_k(Lora2Cfg cfg) {
    const int LDA = 256, N = C_DIM;
    int z = blockIdx.z;
    const __bf16* A  = cfg.A[z];
    const __bf16* BT = cfg.BT[z];
    float* O = cfg.O[z];
    int K = cfg.K[z];

    __shared__ __bf16 As[64 * 32];
    __shared__ __bf16 Bs[128 * 32];
    int tid  = threadIdx.x;
    int lane = tid & 63;
    int wv   = tid >> 6;
    int m    = lane & 15;
    int q    = lane >> 4;
    int wr   = wv >> 1, wc = wv & 1;
    int row0 = blockIdx.x * 64;
    int col0 = blockIdx.y * 128;

    int srow  = tid >> 2;
    int skoff = (tid & 3) * 8;
    const __bf16* agp = A  + (size_t)(row0 + srow) * LDA + skoff;
    const __bf16* bgp = BT + (size_t)(col0 + srow) * K + skoff;
    __bf16* alp = As + (size_t)(tid & ~63) * 8;
    __bf16* blp = Bs + (size_t)(tid & ~63) * 8;

    f32x4 acc[2][4];
#pragma unroll
    for (int i = 0; i < 2; i++)
#pragma unroll
        for (int j = 0; j < 4; j++) acc[i][j] = {0.f, 0.f, 0.f, 0.f};

    for (int k0 = 0; k0 < K; k0 += 32) {
        gll16(agp + k0, alp);
        gll16(bgp + k0, blp);
        gll16(bgp + (size_t)64 * K + k0, blp + 64 * 32);
        __syncthreads();

        bf16x8 af[2], bfv[4];
#pragma unroll
        for (int i = 0; i < 2; i++)
            af[i] = *(const bf16x8*)&As[(wr * 32 + i * 16 + m) * 32 + q * 8];
#pragma unroll
        for (int j = 0; j < 4; j++)
            bfv[j] = *(const bf16x8*)&Bs[(wc * 64 + j * 16 + m) * 32 + q * 8];
#pragma unroll
        for (int i = 0; i < 2; i++)
#pragma unroll
            for (int j = 0; j < 4; j++)
                acc[i][j] = __builtin_amdgcn_mfma_f32_16x16x32_bf16(af[i], bfv[j], acc[i][j], 0, 0, 0);
        __syncthreads();
    }

#pragma unroll
    for (int i = 0; i < 2; i++) {
        int orow = row0 + wr * 32 + i * 16 + q * 4;
#pragma unroll
        for (int j = 0; j < 4; j++) {
            int ocol = col0 + wc * 64 + j * 16 + m;
#pragma unroll
            for (int t = 0; t < 4; t++)
                O[(size_t)(orow + t) * N + ocol] = acc[i][j][t];
        }
    }
}

// ---------------- small GEMM: one wave per 16x16 tile (LoRA stage 1) ----------------
__global__ __launch_bounds__(64) void gemm_bt_w16(
    const __bf16* __restrict__ A, const __bf16* __restrict__ BT,
    float* __restrict__ O, int M, int N, int K) {
    int lane = threadIdx.x & 63;
    int m = lane & 15, q = lane >> 4;
    int row0 = blockIdx.x * 16;
    int col0 = blockIdx.y * 16;
    const __bf16* ap = A  + (size_t)(row0 + m) * K + q * 8;
    const __bf16* bp = BT + (size_t)(col0 + m) * K + q * 8;
    f32x4 acc = {0.f,0.f,0.f,0.f};
    for (int k0 = 0; k0 < K; k0 += 32) {
        bf16x8 av = *(const bf16x8*)(ap + k0);
        bf16x8 bv = *(const bf16x8*)(bp + k0);
        acc = __builtin_amdgcn_mfma_f32_16x16x32_bf16(av, bv, acc, 0, 0, 0);
    }
    int orow = row0 + q * 4;
    int ocol = col0 + m;
#pragma unroll
    for (int i = 0; i < 4; i++)
        O[(size_t)(orow + i) * N + ocol] = acc[i];
}

// ---------------- prep4: gates + FOUR-step composition packing ---------------------------
// (identical to R11 — layout unchanged)
__global__ __launch_bounds__(64) void prep4_k(
    float* __restrict__ rkv,
    const float* __restrict__ vfirst,
    const float* __restrict__ ywb, const float* __restrict__ yab,
    const float* __restrict__ yvb,
    float* __restrict__ pk,
    const float* __restrict__ w0, const float* __restrict__ a0,
    const float* __restrict__ v0, const float* __restrict__ k_k,
    const float* __restrict__ k_a, const float* __restrict__ amask) {
    int tq = blockIdx.x >> 5;
    int h  = blockIdx.x & 31;
    int n  = threadIdx.x;
    int cc = h * HEAD + n;

    float d[4], a[4], b[4], k[4], v[4], r[4];
#pragma unroll
    for (int s = 0; s < 4; ++s) {
        int t = 4 * tq + s;
        int idx = t * C_DIM + cc;
        size_t idx6 = (size_t)t * RKV_N + cc;
        float m  = amask[t];
        float rr = rkv[idx6];
        float kv = rkv[idx6 + 2048];
        float vv = rkv[idx6 + 4096];
        float wv = w0[cc] + ywb[idx];
        float wfin = -log1pf(expf(-wv)) - 0.6f;
        float dec  = expf(-expf(wfin));
        float sv   = 1.f / (1.f + expf(-(v0[cc] + yvb[idx])));
        float vnew = fmaf(vfirst[idx] - vv, sv, vv);
        float av   = 1.f / (1.f + expf(-(a0[cc] + yab[idx])));
        float kkp  = kv * k_k[cc];
        float ss = kkp * kkp;
#pragma unroll
        for (int off = 32; off > 0; off >>= 1) ss += __shfl_xor(ss, off);
        float kkn  = kkp / fmaxf(sqrtf(ss), 1e-12f);
        float knew = kv * (1.f + (av - 1.f) * k_a[cc]);
        d[s] = dec * m + (1.f - m);
        a[s] = -kkn * m;
        b[s] = kkn * av * m;
        k[s] = knew * m;
        v[s] = vnew * m;
        r[s] = rr;
        rkv[idx6 + 2048] = knew;
        rkv[idx6 + 4096] = vnew;
    }

    // stage-A dots (within each double)
    float dA[8] = {b[0]*a[1], k[0]*a[1], b[0]*r[0], k[0]*r[0],
                   b[2]*a[3], k[2]*a[3], b[2]*r[2], k[2]*r[2]};
#pragma unroll
    for (int off = 32; off > 0; off >>= 1)
#pragma unroll
        for (int i = 0; i < 8; ++i) dA[i] += __shfl_xor(dA[i], off);
    float da1 = dA[0], dk1 = dA[1], dbr1 = dA[2], dkr1 = dA[3];
    float da2 = dA[4], dk2 = dA[5], dbr3 = dA[6], dkr3 = dA[7];

    float DDa = d[0] * d[1], DDb = d[2] * d[3];
    float Ba1 = fmaf(da1, b[1], d[1] * b[0]);
    float Ba2 = b[1];
    float Ca1 = fmaf(dk1, b[1], d[1] * k[0]);
    float Ca2 = k[1];
    float Ab1 = a[2];
    float Ab2 = d[2] * a[3];
    float Bb1 = fmaf(da2, b[3], d[3] * b[2]);
    float Bb2 = b[3];
    float Cb1 = fmaf(dk2, b[3], d[3] * k[2]);
    float Cb2 = k[3];
    float u3  = fmaf(dbr3, a[2], d[2] * r[2]);

    // stage-B dots (cross-double + output functionals)
    float dB[16] = {Ba1*Ab1, Ba1*Ab2, Ba2*Ab1, Ba2*Ab2,
                    Ca1*Ab1, Ca1*Ab2, Ca2*Ab1, Ca2*Ab2,
                    Ba1*r[1], Ba2*r[1], Ca1*r[1], Ca2*r[1],
                    Ba1*u3,  Ba2*u3,  Ca1*u3,  Ca2*u3};
#pragma unroll
    for (int off = 32; off > 0; off >>= 1)
#pragma unroll
        for (int i = 0; i < 16; ++i) dB[i] += __shfl_xor(dB[i], off);
    float t11 = dB[0], t12 = dB[1], t21 = dB[2], t22 = dB[3];
    float s11 = dB[4], s12 = dB[5], s21 = dB[6], s22 = dB[7];
    float p1  = dB[8], p2  = dB[9], q1  = dB[10], q2 = dB[11];
    float w1  = dB[12], w2 = dB[13], x1 = dB[14], x2 = dB[15];

    float A2v = d[0] * a[1];
    size_t rec = ((size_t)tq * H_N + h) * REC4;
    pk[rec + 0 * 64 + n]  = DDa * DDb;                              // DD
    pk[rec + 1 * 64 + n]  = a[0];                                   // A1
    pk[rec + 2 * 64 + n]  = A2v;                                    // A2
    pk[rec + 3 * 64 + n]  = DDa * Ab1;                              // A3
    pk[rec + 4 * 64 + n]  = DDa * Ab2;                              // A4
    pk[rec + 5 * 64 + n]  = fmaf(t11, Bb1, fmaf(t12, Bb2, DDb * Ba1)); // B1
    pk[rec + 6 * 64 + n]  = fmaf(t21, Bb1, fmaf(t22, Bb2, DDb * Ba2)); // B2
    pk[rec + 7 * 64 + n]  = Bb1;                                    // B3
    pk[rec + 8 * 64 + n]  = Bb2;                                    // B4
    pk[rec + 9 * 64 + n]  = fmaf(dbr1, a[0], d[0] * r[0]);          // R1
    pk[rec + 10 * 64 + n] = fmaf(p1, a[0], fmaf(p2, A2v, DDa * r[1])); // R2
    pk[rec + 11 * 64 + n] = fmaf(w1, a[0], fmaf(w2, A2v, DDa * u3));   // R3
    pk[rec + 12 * 64 + n] = r[3];                                   // R4
    pk[rec + 13 * 64 + n] = fmaf(s11, Bb1, fmaf(s12, Bb2, DDb * Ca1)); // C1
    pk[rec + 14 * 64 + n] = fmaf(s21, Bb1, fmaf(s22, Bb2, DDb * Ca2)); // C2
    pk[rec + 15 * 64 + n] = Cb1;                                    // C3
    pk[rec + 16 * 64 + n] = Cb2;                                    // C4
    float4 vq = {v[0], v[1], v[2], v[3]};
    *(float4*)&pk[rec + 1088 + 4 * n] = vq;
    float4 oc = {dkr1 * v[0],
                 fmaf(q1, v[0], q2 * v[1]),
                 fmaf(x1, v[0], fmaf(x2, v[1], dkr3 * v[2])),
                 0.f};
    *(float4*)&pk[rec + 1344 + 4 * n] = oc;
}

// ---------------- sequential scan v12: QUAD-STEP, full-width loads + bpermute ------------
// De-duplicates lane replication: lane (jr=lane>>4, c=lane&15) loads array 4i+jr, cols
// [4c,4c+4) — one dwordx4 covers 4 arrays with 64 UNIQUE lanes (7 wave-loads/step vs 19;
// request traffic 19.5KB -> 7KB). Redistribution in-register via __shfl (ds_bpermute,
// compiler-visible dataflow — no wait hazards). R5-proven structure otherwise.
__global__ __launch_bounds__(64, 1) void scan_k(
    const float* __restrict__ pk, float* __restrict__ out) {
    int b = blockIdx.x;
    int xcd  = b & 7;
    int rest = b >> 3;
    int hi   = rest & 3;
    int g    = rest >> 2;
    int h    = xcd + 8 * hi;

    int lane = threadIdx.x;
    int r = lane >> 4;
    int c = lane & 15;
    int row = g * 4 + r;

    float S0 = 0.f, S1 = 0.f, S2 = 0.f, S3 = 0.f;

    float4 D0R[2], D1R[2], D2R[2], D3R[2], D4R[2], VQR[2], OCR[2];

    const size_t tstep = (size_t)H_N * REC4;   // 51200 floats per quad
    const float* base = pk + (size_t)h * REC4;
    const int la = (lane >> 4) * 64 + (lane & 15) * 4;   // lane's packed-array offset
    const int s0 = c, s1 = 16 + c, s2 = 32 + c, s3 = 48 + c;   // bpermute sources

#define LOADSLOT(S_, T_) do {                          \
    const float* L_ = base + (size_t)(T_) * tstep;     \
    D0R[S_] = *(const float4*)(L_ + 0 * 256 + la);     \
    D1R[S_] = *(const float4*)(L_ + 1 * 256 + la);     \
    D2R[S_] = *(const float4*)(L_ + 2 * 256 + la);     \
    D3R[S_] = *(const float4*)(L_ + 3 * 256 + la);     \
    D4R[S_] = *(const float4*)(L_ + 4 * 256 + la);     \
    VQR[S_] = *(const float4*)(L_ + 1088 + 4 * row);   \
    OCR[S_] = *(const float4*)(L_ + 1344 + 4 * row);   \
} while (0)

    LOADSLOT(0, 0);
    LOADSLOT(1, 1);
    __builtin_amdgcn_sched_barrier(0);

    int off = h * HEAD;

#define SCAN_STEP(SS, TQ) do {                                                \
    float4 D0v = D0R[SS], D1v = D1R[SS], D2v = D2R[SS], D3v = D3R[SS];        \
    float4 D4v = D4R[SS];                                                     \
    float4 vq = VQR[SS], oc = OCR[SS];                                        \
    int tn = (TQ) + 2;                                                        \
    if (tn > NQ - 1) tn = NQ - 1;                                             \
    LOADSLOT(SS, tn);                                                         \
    __builtin_amdgcn_sched_barrier(0);                                        \
    /* redistribute: array j col-slice c comes from lane (j&3)*16 + c */      \
    float4 DDv = shfl4(D0v, s0);                                              \
    float4 A1v = shfl4(D0v, s1);                                              \
    float4 A2v = shfl4(D0v, s2);                                              \
    float4 A3v = shfl4(D0v, s3);                                              \
    float4 A4v = shfl4(D1v, s0);                                              \
    float4 B1v = shfl4(D1v, s1);                                              \
    float4 B2v = shfl4(D1v, s2);                                              \
    float4 B3v = shfl4(D1v, s3);                                              \
    float4 B4v = shfl4(D2v, s0);                                              \
    float4 R1v = shfl4(D2v, s1);                                              \
    float4 R2v = shfl4(D2v, s2);                                              \
    float4 R3v = shfl4(D2v, s3);                                              \
    float4 R4v = shfl4(D3v, s0);                                              \
    float4 C1v = shfl4(D3v, s1);                                              \
    float4 C2v = shfl4(D3v, s2);                                              \
    float4 C3v = shfl4(D3v, s3);                                              \
    float4 C4v = shfl4(D4v, s0);                                              \
    /* 7 parallel reduces on S_pre */                                         \
    float sa1 = hex_add(fmaf(S0, A1v.x, S1 * A1v.y) + fmaf(S2, A1v.z, S3 * A1v.w)); \
    float sa2 = hex_add(fmaf(S0, A2v.x, S1 * A2v.y) + fmaf(S2, A2v.z, S3 * A2v.w)); \
    float sa3 = hex_add(fmaf(S0, A3v.x, S1 * A3v.y) + fmaf(S2, A3v.z, S3 * A3v.w)); \
    float sa4 = hex_add(fmaf(S0, A4v.x, S1 * A4v.y) + fmaf(S2, A4v.z, S3 * A4v.w)); \
    float so1 = hex_add(fmaf(S0, R1v.x, S1 * R1v.y) + fmaf(S2, R1v.z, S3 * R1v.w)); \
    float so2 = hex_add(fmaf(S0, R2v.x, S1 * R2v.y) + fmaf(S2, R2v.z, S3 * R2v.w)); \
    float so3 = hex_add(fmaf(S0, R3v.x, S1 * R3v.y) + fmaf(S2, R3v.z, S3 * R3v.w)); \
    if (c == 0) {                                                             \
        out[off + row]             = so1 + oc.x;                              \
        out[off + C_DIM + row]     = so2 + oc.y;                              \
        out[off + 2 * C_DIM + row] = so3 + oc.z;                              \
    }                                                                         \
    /* update: S = S*DD + sum saj*Bj + sum vj*Cj */                           \
    float t0 = fmaf(vq.x, C1v.x, fmaf(vq.y, C2v.x, fmaf(vq.z, C3v.x, vq.w * C4v.x))); \
    float t1 = fmaf(vq.x, C1v.y, fmaf(vq.y, C2v.y, fmaf(vq.z, C3v.y, vq.w * C4v.y))); \
    float t2 = fmaf(vq.x, C1v.z, fmaf(vq.y, C2v.z, fmaf(vq.z, C3v.z, vq.w * C4v.z))); \
    float t3 = fmaf(vq.x, C1v.w, fmaf(vq.y, C2v.w, fmaf(vq.z, C3v.w, vq.w * C4v.w))); \
    t0 = fmaf(sa1, B1v.x, fmaf(sa2, B2v.x, fmaf(sa3, B3v.x, fmaf(sa4, B4v.x, t0)))); \
    t1 = fmaf(sa1, B1v.y, fmaf(sa2, B2v.y, fmaf(sa3, B3v.y, fmaf(sa4, B4v.y, t1)))); \
    t2 = fmaf(sa1, B1v.z, fmaf(sa2, B2v.z, fmaf(sa3, B3v.z, fmaf(sa4, B4v.z, t2)))); \
    t3 = fmaf(sa1, B1v.w, fmaf(sa2, B2v.w, fmaf(sa3, B3v.w, fmaf(sa4, B4v.w, t3)))); \
    S0 = fmaf(DDv.x, S0, t0);                                                 \
    S1 = fmaf(DDv.y, S1, t1);                                                 \
    S2 = fmaf(DDv.z, S2, t2);                                                 \
    S3 = fmaf(DDv.w, S3, t3);                                                 \
    /* out4 on post-update S */                                               \
    float o0 = fmaf(S0, R4v.x, S1 * R4v.y);                                   \
    float o1 = fmaf(S2, R4v.z, S3 * R4v.w);                                   \
    float op = hex_add(o0 + o1);                                              \
    if (c == 0) out[off + 3 * C_DIM + row] = op;                              \
    off += 4 * C_DIM;                                                         \
    __builtin_amdgcn_sched_barrier(0);                                        \
} while (0)

#pragma unroll 1
    for (int tq0 = 0; tq0 < NQ; tq0 += 2) {
        SCAN_STEP(0, tq0);
        SCAN_STEP(1, tq0 + 1);
    }
#undef SCAN_STEP
#undef LOADSLOT
}

// ---------------- residual + cast + v_first passthrough ----------------
__global__ __launch_bounds__(64) void resid_k(
    const float* __restrict__ rkv, const float* __restrict__ souts,
    const float* __restrict__ r_k, const float* __restrict__ vfirst,
    __bf16* __restrict__ ob, float* __restrict__ dout) {
    int t = blockIdx.x >> 5;
    int h = blockIdx.x & 31;
    int n = threadIdx.x;
    int cc  = h * HEAD + n;
    int idx = t * C_DIM + cc;
    size_t idx6 = (size_t)t * RKV_N + cc;
    float s = rkv[idx6] * rkv[idx6 + 2048] * r_k[cc];
#pragma unroll
    for (int off = 32; off > 0; off >>= 1) s += __shfl_xor(s, off);
    float ov = souts[idx] + s * rkv[idx6 + 4096];
    ob[idx] = (__bf16)ov;
    dout[BTC + idx] = vfirst[idx];
}

// ---------------- host launcher ----------------
extern "C" void kernel_launch(void* const* d_in, const int* in_sizes, int n_in,
                              void* d_out, int out_size, void* d_ws, size_t ws_size,
                              hipStream_t stream) {
    const float* x      = (const float*)d_in[0];
    const float* vfirst = (const float*)d_in[1];
    const float* amask  = (const float*)d_in[2];
    const float* w0 = (const float*)d_in[3];
    const float* w1 = (const float*)d_in[4];
    const float* w2 = (const float*)d_in[5];
    const float* a0 = (const float*)d_in[6];
    const float* a1 = (const float*)d_in[7];
    const float* a2 = (const float*)d_in[8];
    const float* v0 = (const float*)d_in[9];
    const float* v1 = (const float*)d_in[10];
    const float* v2 = (const float*)d_in[11];
    const float* k_k = (const float*)d_in[12];
    const float* k_a = (const float*)d_in[13];
    const float* r_k = (const float*)d_in[14];
    const float* Wr = (const float*)d_in[15];
    const float* Wk = (const float*)d_in[16];
    const float* Wv = (const float*)d_in[17];
    const float* Wo = (const float*)d_in[18];
    float* dout = (float*)d_out;

    char* wp = (char*)d_ws;
    auto alloc = [&](size_t bytes) -> void* {
        void* p = (void*)wp;
        wp += (bytes + 255) & ~(size_t)255;
        return p;
    };
    __bf16* xb     = (__bf16*)alloc((size_t)BTC * 2);
    __bf16* rkvT   = (__bf16*)alloc((size_t)3 * C_DIM * C_DIM * 2);
    __bf16* WoT    = (__bf16*)alloc((size_t)C_DIM * C_DIM * 2);
    __bf16* lora1T = (__bf16*)alloc((size_t)256 * C_DIM * 2);
    __bf16* w2T = (__bf16*)alloc((size_t)C_DIM * 96 * 2);
    __bf16* a2T = (__bf16*)alloc((size_t)C_DIM * 96 * 2);
    __bf16* v2T = (__bf16*)alloc((size_t)C_DIM * 64 * 2);
    float*  rkv = (float*)alloc((size_t)T_LEN * RKV_N * 4);
    float*  hall  = (float*)alloc((size_t)T_LEN * 256 * 4);
    __bf16* hallb = (__bf16*)alloc((size_t)T_LEN * 256 * 2);
    float*  ywb = (float*)alloc((size_t)BTC * 4);
    float*  yab = (float*)alloc((size_t)BTC * 4);
    float*  yvb = (float*)alloc((size_t)BTC * 4);
    float*  pk  = (float*)alloc((size_t)NQ * H_N * REC4 * 4 + 4096);
    float*  souts = (float*)alloc((size_t)BTC * 4);
    __bf16* ob  = (__bf16*)alloc((size_t)BTC * 2);

    // 1) cast x -> bf16
    cast_bf16_k<<<dim3(BTC / 256), 256, 0, stream>>>(x, xb, BTC);

    // 2) ALL weight transposes in one launch
    TransBatch tb;
    tb.s[0] = Wr; tb.d[0] = rkvT;                              tb.R[0] = C_DIM; tb.C[0] = C_DIM;
    tb.s[1] = Wk; tb.d[1] = rkvT + (size_t)C_DIM * C_DIM;      tb.R[1] = C_DIM; tb.C[1] = C_DIM;
    tb.s[2] = Wv; tb.d[2] = rkvT + (size_t)2 * C_DIM * C_DIM;  tb.R[2] = C_DIM; tb.C[2] = C_DIM;
    tb.s[3] = Wo; tb.d[3] = WoT;                               tb.R[3] = C_DIM; tb.C[3] = C_DIM;
    tb.s[4] = w1; tb.d[4] = lora1T;                            tb.R[4] = C_DIM; tb.C[4] = 96;
    tb.s[5] = a1; tb.d[5] = lora1T + (size_t)96 * C_DIM;       tb.R[5] = C_DIM; tb.C[5] = 96;
    tb.s[6] = v1; tb.d[6] = lora1T + (size_t)192 * C_DIM;      tb.R[6] = C_DIM; tb.C[6] = 64;
    tb.s[7] = w2; tb.d[7] = w2T;                               tb.R[7] = 96;    tb.C[7] = C_DIM;
    tb.s[8] = a2; tb.d[8] = a2T;                               tb.R[8] = 96;    tb.C[8] = C_DIM;
    tb.s[9] = v2; tb.d[9] = v2T;                               tb.R[9] = 64;    tb.C[9] = C_DIM;
    transpose_batch_k<<<dim3(64, 64, 10), dim3(32, 8), 0, stream>>>(tb);

    // 3) fused big GEMM: rkv = xb @ [Wr|Wk|Wv]  (128x128 tiles)
    gemm_lds_128x128<<<dim3(8, 48), 256, 0, stream>>>(xb, rkvT, rkv, T_LEN, RKV_N, C_DIM);

    // 4) fused LoRA first stage: hall = xb @ [w1|a1|v1]
    gemm_bt_w16<<<dim3(64, 16), 64, 0, stream>>>(xb, lora1T, hall, T_LEN, 256, C_DIM);

    // 5) fused activation + cast
    act_lora1_k<<<dim3(T_LEN * 256 / 256), 256, 0, stream>>>(hall, hallb);

    // 6) fused LoRA second stage (grid.z = 3)
    Lora2Cfg lc;
    lc.A[0] = hallb;       lc.BT[0] = w2T; lc.O[0] = ywb; lc.K[0] = 96;
    lc.A[1] = hallb + 96;  lc.BT[1] = a2T; lc.O[1] = yab; lc.K[1] = 96;
    lc.A[2] = hallb + 192; lc.BT[2] = v2T; lc.O[2] = yvb; lc.K[2] = 64;
    gemm_lora2_k<<<dim3(16, 16, 3), 256, 0, stream>>>(lc);

    // 7) prep4: gates + QUAD-step composition packing
    prep4_k<<<dim3(NQ * H_N), 64, 0, stream>>>(rkv, vfirst, ywb, yab, yvb,
                                               pk, w0, a0, v0, k_k, k_a, amask);

    // 8) sequential scan v12: quad-step, full-width loads + bpermute redistribution
    scan_k<<<dim3(H_N * 16), 64, 0, stream>>>(pk, souts);

    // 9) residual + cast + v_first passthrough
    resid_k<<<dim3(T_LEN * H_N), 64, 0, stream>>>(rkv, souts, r_k, vfirst, ob, dout);

    // 10) final GEMM: dout[0:BTC] = ob @ Wo
    gemm_lds_64x128<<<dim3(16, 16), 256, 0, stream>>>(ob, WoT, dout, T_LEN, C_DIM, C_DIM);
}

// Round 13
// 442.395 us; speedup vs baseline: 1.1651x; 1.1651x over previous
//
#include <hip/hip_runtime.h>
#include <math.h>

#define T_LEN 1024
#define C_DIM 2048
#define H_N   32
#define HEAD  64
#define BTC   (T_LEN * C_DIM)
#define REC4  1600  // floats per (t-quad,h): [DD|A1-4|B1-4|R1-4|C1-4]x64 + vq[256] + oc[256]
#define RKV_N 6144
#define NQ    (T_LEN / 4)   // 256 quad-steps

typedef __attribute__((ext_vector_type(8))) __bf16 bf16x8;
typedef __attribute__((ext_vector_type(4))) float  f32x4;

// ---------------- async global->LDS helper (16B/lane, wave-uniform LDS base) -------------
__device__ __forceinline__ void gll16(const void* g, void* l) {
    __builtin_amdgcn_global_load_lds((const __attribute__((address_space(1))) void*)g,
                                     (__attribute__((address_space(3))) void*)l, 16, 0, 0);
}

// 16-lane reduce, pure DPP
__device__ __forceinline__ float hex_add(float x) {
    int a = __builtin_amdgcn_mov_dpp(__float_as_int(x), 0xB1, 0xF, 0xF, true);   // quad_perm [1,0,3,2]
    float y = x + __int_as_float(a);
    int b = __builtin_amdgcn_mov_dpp(__float_as_int(y), 0x4E, 0xF, 0xF, true);   // quad_perm [2,3,0,1]
    float z = y + __int_as_float(b);
    int c = __builtin_amdgcn_mov_dpp(__float_as_int(z), 0x141, 0xF, 0xF, true);  // row_half_mirror
    float w = z + __int_as_float(c);
    int d = __builtin_amdgcn_mov_dpp(__float_as_int(w), 0x140, 0xF, 0xF, true);  // row_mirror
    return w + __int_as_float(d);
}

// ---------------- cast x -> bf16 ----------------
__global__ void cast_bf16_k(const float* __restrict__ s, __bf16* __restrict__ d, int n) {
    int i = blockIdx.x * 256 + threadIdx.x;
    if (i < n) d[i] = (__bf16)s[i];
}

// ---------------- batched transpose + cast ------------
struct TransBatch {
    const float* s[10];
    __bf16*      d[10];
    int R[10];
    int C[10];
};
__global__ void transpose_batch_k(TransBatch tb) {
    int z = blockIdx.z;
    const float* src = tb.s[z];
    __bf16* dst = tb.d[z];
    int R = tb.R[z], C = tb.C[z];
    int c0 = blockIdx.x * 32, r0 = blockIdx.y * 32;
    if (c0 >= C || r0 >= R) return;
    __shared__ float tile[32][33];
    int tx = threadIdx.x, ty = threadIdx.y;
#pragma unroll
    for (int i = 0; i < 32; i += 8)
        tile[ty + i][tx] = src[(size_t)(r0 + ty + i) * C + c0 + tx];
    __syncthreads();
#pragma unroll
    for (int i = 0; i < 32; i += 8)
        dst[(size_t)(c0 + ty + i) * R + r0 + tx] = (__bf16)tile[tx][ty + i];
}

// ---------------- GEMM 64x128 tile ----------------
__global__ __launch_bounds__(256) void gemm_lds_64x128(
    const __bf16* __restrict__ A, const __bf16* __restrict__ BT,
    float* __restrict__ O, int M, int N, int K) {
    __shared__ __bf16 As[64 * 32];
    __shared__ __bf16 Bs[128 * 32];
    int tid  = threadIdx.x;
    int lane = tid & 63;
    int wv   = tid >> 6;
    int m    = lane & 15;
    int q    = lane >> 4;
    int wr   = wv >> 1, wc = wv & 1;
    int row0 = blockIdx.x * 64;
    int col0 = blockIdx.y * 128;

    int srow  = tid >> 2;
    int skoff = (tid & 3) * 8;
    const __bf16* agp = A  + (size_t)(row0 + srow) * K + skoff;
    const __bf16* bgp = BT + (size_t)(col0 + srow) * K + skoff;
    __bf16* alp = As + (size_t)(tid & ~63) * 8;
    __bf16* blp = Bs + (size_t)(tid & ~63) * 8;

    f32x4 acc[2][4];
#pragma unroll
    for (int i = 0; i < 2; i++)
#pragma unroll
        for (int j = 0; j < 4; j++) acc[i][j] = {0.f, 0.f, 0.f, 0.f};

    for (int k0 = 0; k0 < K; k0 += 32) {
        gll16(agp + k0, alp);
        gll16(bgp + k0, blp);
        gll16(bgp + (size_t)64 * K + k0, blp + 64 * 32);
        __syncthreads();

        bf16x8 af[2], bfv[4];
#pragma unroll
        for (int i = 0; i < 2; i++)
            af[i] = *(const bf16x8*)&As[(wr * 32 + i * 16 + m) * 32 + q * 8];
#pragma unroll
        for (int j = 0; j < 4; j++)
            bfv[j] = *(const bf16x8*)&Bs[(wc * 64 + j * 16 + m) * 32 + q * 8];
#pragma unroll
        for (int i = 0; i < 2; i++)
#pragma unroll
            for (int j = 0; j < 4; j++)
                acc[i][j] = __builtin_amdgcn_mfma_f32_16x16x32_bf16(af[i], bfv[j], acc[i][j], 0, 0, 0);
        __syncthreads();
    }

#pragma unroll
    for (int i = 0; i < 2; i++) {
        int orow = row0 + wr * 32 + i * 16 + q * 4;
#pragma unroll
        for (int j = 0; j < 4; j++) {
            int ocol = col0 + wc * 64 + j * 16 + m;
#pragma unroll
            for (int t = 0; t < 4; t++)
                O[(size_t)(orow + t) * N + ocol] = acc[i][j][t];
        }
    }
}

// ---------------- GEMM 128x128 tile (big rkv GEMM) ----------------
__global__ __launch_bounds__(256) void gemm_lds_128x128(
    const __bf16* __restrict__ A, const __bf16* __restrict__ BT,
    float* __restrict__ O, int M, int N, int K) {
    __shared__ __bf16 As[128 * 32];
    __shared__ __bf16 Bs[128 * 32];
    int tid  = threadIdx.x;
    int lane = tid & 63;
    int wv   = tid >> 6;
    int m    = lane & 15;
    int q    = lane >> 4;
    int row0 = blockIdx.x * 128;
    int col0 = blockIdx.y * 128;

    int srow  = tid >> 2;
    int skoff = (tid & 3) * 8;
    const __bf16* agp = A  + (size_t)(row0 + srow) * K + skoff;
    const __bf16* bgp = BT + (size_t)(col0 + srow) * K + skoff;
    __bf16* alp = As + (size_t)(tid & ~63) * 8;
    __bf16* blp = Bs + (size_t)(tid & ~63) * 8;

    f32x4 acc[2][8];
#pragma unroll
    for (int i = 0; i < 2; i++)
#pragma unroll
        for (int j = 0; j < 8; j++) acc[i][j] = {0.f, 0.f, 0.f, 0.f};

    for (int k0 = 0; k0 < K; k0 += 32) {
        gll16(agp + k0, alp);
        gll16(agp + (size_t)64 * K + k0, alp + 64 * 32);
        gll16(bgp + k0, blp);
        gll16(bgp + (size_t)64 * K + k0, blp + 64 * 32);
        __syncthreads();

        bf16x8 af[2], bfv[8];
#pragma unroll
        for (int i = 0; i < 2; i++)
            af[i] = *(const bf16x8*)&As[(wv * 32 + i * 16 + m) * 32 + q * 8];
#pragma unroll
        for (int j = 0; j < 8; j++)
            bfv[j] = *(const bf16x8*)&Bs[(j * 16 + m) * 32 + q * 8];
#pragma unroll
        for (int i = 0; i < 2; i++)
#pragma unroll
            for (int j = 0; j < 8; j++)
                acc[i][j] = __builtin_amdgcn_mfma_f32_16x16x32_bf16(af[i], bfv[j], acc[i][j], 0, 0, 0);
        __syncthreads();
    }

#pragma unroll
    for (int i = 0; i < 2; i++) {
        int orow = row0 + wv * 32 + i * 16 + q * 4;
#pragma unroll
        for (int j = 0; j < 8; j++) {
            int ocol = col0 + j * 16 + m;
#pragma unroll
            for (int t = 0; t < 4; t++)
                O[(size_t)(orow + t) * N + ocol] = acc[i][j][t];
        }
    }
}

// ---------------- fused LoRA-2 GEMM (grid.z = 3) ----------------
struct Lora2Cfg {
    const __bf16* A[3];
    const __bf16* BT[3];
    float*        O[3];
    int K[3];
};
__global__ __launch_bounds__(256) void gemm_lora2_k(Lora2Cfg cfg) {
    const int LDA = 256, N = C_DIM;
    int z = blockIdx.z;
    const __bf16* A  = cfg.A[z];
    const __bf16* BT = cfg.BT[z];
    float* O = cfg.O[z];
    int K = cfg.K[z];

    __shared__ __bf16 As[64 * 32];
    __shared__ __bf16 Bs[128 * 32];
    int tid  = threadIdx.x;
    int lane = tid & 63;
    int wv   = tid >> 6;
    int m    = lane & 15;
    int q    = lane >> 4;
    int wr   = wv >> 1, wc = wv & 1;
    int row0 = blockIdx.x * 64;
    int col0 = blockIdx.y * 128;

    int srow  = tid >> 2;
    int skoff = (tid & 3) * 8;
    const __bf16* agp = A  + (size_t)(row0 + srow) * LDA + skoff;
    const __bf16* bgp = BT + (size_t)(col0 + srow) * K + skoff;
    __bf16* alp = As + (size_t)(tid & ~63) * 8;
    __bf16* blp = Bs + (size_t)(tid & ~63) * 8;

    f32x4 acc[2][4];
#pragma unroll
    for (int i = 0; i < 2; i++)
#pragma unroll
        for (int j = 0; j < 4; j++) acc[i][j] = {0.f, 0.f, 0.f, 0.f};

    for (int k0 = 0; k0 < K; k0 += 32) {
        gll16(agp + k0, alp);
        gll16(bgp + k0, blp);
        gll16(bgp + (size_t)64 * K + k0, blp + 64 * 32);
        __syncthreads();

        bf16x8 af[2], bfv[4];
#pragma unroll
        for (int i = 0; i < 2; i++)
            af[i] = *(const bf16x8*)&As[(wr * 32 + i * 16 + m) * 32 + q * 8];
#pragma unroll
        for (int j = 0; j < 4; j++)
            bfv[j] = *(const bf16x8*)&Bs[(wc * 64 + j * 16 + m) * 32 + q * 8];
#pragma unroll
        for (int i = 0; i < 2; i++)
#pragma unroll
            for (int j = 0; j < 4; j++)
                acc[i][j] = __builtin_amdgcn_mfma_f32_16x16x32_bf16(af[i], bfv[j], acc[i][j], 0, 0, 0);
        __syncthreads();
    }

#pragma unroll
    for (int i = 0; i < 2; i++) {
        int orow = row0 + wr * 32 + i * 16 + q * 4;
#pragma unroll
        for (int j = 0; j < 4; j++) {
            int ocol = col0 + wc * 64 + j * 16 + m;
#pragma unroll
            for (int t = 0; t < 4; t++)
                O[(size_t)(orow + t) * N + ocol] = acc[i][j][t];
        }
    }
}

// ---------------- LoRA-1 GEMM with fused activation epilogue (tanh on cols<96) -----------
// one wave per 16x16 tile; writes bf16 directly (act_lora1_k fused away).
__global__ __launch_bounds__(64) void gemm_lora1_k(
    const __bf16* __restrict__ A, const __bf16* __restrict__ BT,
    __bf16* __restrict__ O, int M, int N, int K) {
    int lane = threadIdx.x & 63;
    int m = lane & 15, q = lane >> 4;
    int row0 = blockIdx.x * 16;
    int col0 = blockIdx.y * 16;
    const __bf16* ap = A  + (size_t)(row0 + m) * K + q * 8;
    const __bf16* bp = BT + (size_t)(col0 + m) * K + q * 8;
    f32x4 acc = {0.f,0.f,0.f,0.f};
    for (int k0 = 0; k0 < K; k0 += 32) {
        bf16x8 av = *(const bf16x8*)(ap + k0);
        bf16x8 bv = *(const bf16x8*)(bp + k0);
        acc = __builtin_amdgcn_mfma_f32_16x16x32_bf16(av, bv, acc, 0, 0, 0);
    }
    int orow = row0 + q * 4;
    int ocol = col0 + m;
    bool act = (ocol < 96);
#pragma unroll
    for (int i = 0; i < 4; i++) {
        float v = acc[i];
        if (act) v = tanhf(v);
        O[(size_t)(orow + i) * N + ocol] = (__bf16)v;
    }
}

// ---------------- prep4: gates + FOUR-step composition packing (unchanged from R11) ------
__global__ __launch_bounds__(64) void prep4_k(
    float* __restrict__ rkv,
    const float* __restrict__ vfirst,
    const float* __restrict__ ywb, const float* __restrict__ yab,
    const float* __restrict__ yvb,
    float* __restrict__ pk,
    const float* __restrict__ w0, const float* __restrict__ a0,
    const float* __restrict__ v0, const float* __restrict__ k_k,
    const float* __restrict__ k_a, const float* __restrict__ amask) {
    int tq = blockIdx.x >> 5;
    int h  = blockIdx.x & 31;
    int n  = threadIdx.x;
    int cc = h * HEAD + n;

    float d[4], a[4], b[4], k[4], v[4], r[4];
#pragma unroll
    for (int s = 0; s < 4; ++s) {
        int t = 4 * tq + s;
        int idx = t * C_DIM + cc;
        size_t idx6 = (size_t)t * RKV_N + cc;
        float m  = amask[t];
        float rr = rkv[idx6];
        float kv = rkv[idx6 + 2048];
        float vv = rkv[idx6 + 4096];
        float wv = w0[cc] + ywb[idx];
        float wfin = -log1pf(expf(-wv)) - 0.6f;
        float dec  = expf(-expf(wfin));
        float sv   = 1.f / (1.f + expf(-(v0[cc] + yvb[idx])));
        float vnew = fmaf(vfirst[idx] - vv, sv, vv);
        float av   = 1.f / (1.f + expf(-(a0[cc] + yab[idx])));
        float kkp  = kv * k_k[cc];
        float ss = kkp * kkp;
#pragma unroll
        for (int off = 32; off > 0; off >>= 1) ss += __shfl_xor(ss, off);
        float kkn  = kkp / fmaxf(sqrtf(ss), 1e-12f);
        float knew = kv * (1.f + (av - 1.f) * k_a[cc]);
        d[s] = dec * m + (1.f - m);
        a[s] = -kkn * m;
        b[s] = kkn * av * m;
        k[s] = knew * m;
        v[s] = vnew * m;
        r[s] = rr;
        rkv[idx6 + 2048] = knew;
        rkv[idx6 + 4096] = vnew;
    }

    // stage-A dots (within each double)
    float dA[8] = {b[0]*a[1], k[0]*a[1], b[0]*r[0], k[0]*r[0],
                   b[2]*a[3], k[2]*a[3], b[2]*r[2], k[2]*r[2]};
#pragma unroll
    for (int off = 32; off > 0; off >>= 1)
#pragma unroll
        for (int i = 0; i < 8; ++i) dA[i] += __shfl_xor(dA[i], off);
    float da1 = dA[0], dk1 = dA[1], dbr1 = dA[2], dkr1 = dA[3];
    float da2 = dA[4], dk2 = dA[5], dbr3 = dA[6], dkr3 = dA[7];

    float DDa = d[0] * d[1], DDb = d[2] * d[3];
    float Ba1 = fmaf(da1, b[1], d[1] * b[0]);
    float Ba2 = b[1];
    float Ca1 = fmaf(dk1, b[1], d[1] * k[0]);
    float Ca2 = k[1];
    float Ab1 = a[2];
    float Ab2 = d[2] * a[3];
    float Bb1 = fmaf(da2, b[3], d[3] * b[2]);
    float Bb2 = b[3];
    float Cb1 = fmaf(dk2, b[3], d[3] * k[2]);
    float Cb2 = k[3];
    float u3  = fmaf(dbr3, a[2], d[2] * r[2]);

    // stage-B dots (cross-double + output functionals)
    float dB[16] = {Ba1*Ab1, Ba1*Ab2, Ba2*Ab1, Ba2*Ab2,
                    Ca1*Ab1, Ca1*Ab2, Ca2*Ab1, Ca2*Ab2,
                    Ba1*r[1], Ba2*r[1], Ca1*r[1], Ca2*r[1],
                    Ba1*u3,  Ba2*u3,  Ca1*u3,  Ca2*u3};
#pragma unroll
    for (int off = 32; off > 0; off >>= 1)
#pragma unroll
        for (int i = 0; i < 16; ++i) dB[i] += __shfl_xor(dB[i], off);
    float t11 = dB[0], t12 = dB[1], t21 = dB[2], t22 = dB[3];
    float s11 = dB[4], s12 = dB[5], s21 = dB[6], s22 = dB[7];
    float p1  = dB[8], p2  = dB[9], q1  = dB[10], q2 = dB[11];
    float w1  = dB[12], w2 = dB[13], x1 = dB[14], x2 = dB[15];

    float A2v = d[0] * a[1];
    size_t rec = ((size_t)tq * H_N + h) * REC4;
    pk[rec + 0 * 64 + n]  = DDa * DDb;                              // DD
    pk[rec + 1 * 64 + n]  = a[0];                                   // A1
    pk[rec + 2 * 64 + n]  = A2v;                                    // A2
    pk[rec + 3 * 64 + n]  = DDa * Ab1;                              // A3
    pk[rec + 4 * 64 + n]  = DDa * Ab2;                              // A4
    pk[rec + 5 * 64 + n]  = fmaf(t11, Bb1, fmaf(t12, Bb2, DDb * Ba1)); // B1
    pk[rec + 6 * 64 + n]  = fmaf(t21, Bb1, fmaf(t22, Bb2, DDb * Ba2)); // B2
    pk[rec + 7 * 64 + n]  = Bb1;                                    // B3
    pk[rec + 8 * 64 + n]  = Bb2;                                    // B4
    pk[rec + 9 * 64 + n]  = fmaf(dbr1, a[0], d[0] * r[0]);          // R1
    pk[rec + 10 * 64 + n] = fmaf(p1, a[0], fmaf(p2, A2v, DDa * r[1])); // R2
    pk[rec + 11 * 64 + n] = fmaf(w1, a[0], fmaf(w2, A2v, DDa * u3));   // R3
    pk[rec + 12 * 64 + n] = r[3];                                   // R4
    pk[rec + 13 * 64 + n] = fmaf(s11, Bb1, fmaf(s12, Bb2, DDb * Ca1)); // C1
    pk[rec + 14 * 64 + n] = fmaf(s21, Bb1, fmaf(s22, Bb2, DDb * Ca2)); // C2
    pk[rec + 15 * 64 + n] = Cb1;                                    // C3
    pk[rec + 16 * 64 + n] = Cb2;                                    // C4
    float4 vq = {v[0], v[1], v[2], v[3]};
    *(float4*)&pk[rec + 1088 + 4 * n] = vq;
    float4 oc = {dkr1 * v[0],
                 fmaf(q1, v[0], q2 * v[1]),
                 fmaf(x1, v[0], fmaf(x2, v[1], dkr3 * v[2])),
                 0.f};
    *(float4*)&pk[rec + 1344 + 4 * n] = oc;
}

// ---------------- sequential scan v13: QUAD-STEP, packed loads + LDS-bounce --------------
// R12's de-duplicated 7-load format (lane jr=lane>>4 loads arrays 4i+jr, cols [4c,4c+4))
// with redistribution through a 5KB LDS scratch instead of bpermute: 5 ds_write_b128 +
// 17 ds_read_b128 per step (in-order DS pipe, single wave, no barriers, compiler waits).
// Ring-2 register prefetch (R5-proven). Reads broadcast across the 4 r-groups (free);
// 2-way bank alias on reads is free (m136).
__global__ __launch_bounds__(64, 1) void scan_k(
    const float* __restrict__ pk, float* __restrict__ out) {
    int b = blockIdx.x;
    int xcd  = b & 7;
    int rest = b >> 3;
    int hi   = rest & 3;
    int g    = rest >> 2;
    int h    = xcd + 8 * hi;

    int lane = threadIdx.x;
    int r = lane >> 4;
    int c = lane & 15;
    int row = g * 4 + r;
    int jb  = c * 4;

    __shared__ float slab[1280];   // packed arrays 0..19 (17 used), 5 KB

    float S0 = 0.f, S1 = 0.f, S2 = 0.f, S3 = 0.f;

    f32x4 D0R[2], D1R[2], D2R[2], D3R[2], D4R[2], VQR[2], OCR[2];

    const size_t tstep = (size_t)H_N * REC4;   // 51200 floats per quad
    const float* base = pk + (size_t)h * REC4;
    const int la = r * 64 + jb;                // lane's packed-array slot (load & write)

#define LOADSLOT(S_, T_) do {                          \
    const float* L_ = base + (size_t)(T_) * tstep;     \
    D0R[S_] = *(const f32x4*)(L_ + 0 * 256 + la);      \
    D1R[S_] = *(const f32x4*)(L_ + 1 * 256 + la);      \
    D2R[S_] = *(const f32x4*)(L_ + 2 * 256 + la);      \
    D3R[S_] = *(const f32x4*)(L_ + 3 * 256 + la);      \
    D4R[S_] = *(const f32x4*)(L_ + 4 * 256 + la);      \
    VQR[S_] = *(const f32x4*)(L_ + 1088 + 4 * row);    \
    OCR[S_] = *(const f32x4*)(L_ + 1344 + 4 * row);    \
} while (0)

    LOADSLOT(0, 0);
    LOADSLOT(1, 1);
    __builtin_amdgcn_sched_barrier(0);

    int off = h * HEAD;

#define SCAN_STEP(SS, TQ) do {                                                \
    /* bounce packed regs through LDS (in-order DS, single wave) */           \
    *(f32x4*)&slab[0 * 256 + la] = D0R[SS];                                   \
    *(f32x4*)&slab[1 * 256 + la] = D1R[SS];                                   \
    *(f32x4*)&slab[2 * 256 + la] = D2R[SS];                                   \
    *(f32x4*)&slab[3 * 256 + la] = D3R[SS];                                   \
    *(f32x4*)&slab[4 * 256 + la] = D4R[SS];                                   \
    float4 vq = {VQR[SS][0], VQR[SS][1], VQR[SS][2], VQR[SS][3]};             \
    float4 oc = {OCR[SS][0], OCR[SS][1], OCR[SS][2], OCR[SS][3]};             \
    int tn = (TQ) + 2;                                                        \
    if (tn > NQ - 1) tn = NQ - 1;                                             \
    LOADSLOT(SS, tn);                                                         \
    __builtin_amdgcn_sched_barrier(0);                                        \
    /* read the 17 arrays at this lane's column slice */                      \
    f32x4 DDv = *(const f32x4*)&slab[0 * 64 + jb];                            \
    f32x4 A1v = *(const f32x4*)&slab[1 * 64 + jb];                            \
    f32x4 A2v = *(const f32x4*)&slab[2 * 64 + jb];                            \
    f32x4 A3v = *(const f32x4*)&slab[3 * 64 + jb];                            \
    f32x4 A4v = *(const f32x4*)&slab[4 * 64 + jb];                            \
    f32x4 B1v = *(const f32x4*)&slab[5 * 64 + jb];                            \
    f32x4 B2v = *(const f32x4*)&slab[6 * 64 + jb];                            \
    f32x4 B3v = *(const f32x4*)&slab[7 * 64 + jb];                            \
    f32x4 B4v = *(const f32x4*)&slab[8 * 64 + jb];                            \
    f32x4 R1v = *(const f32x4*)&slab[9 * 64 + jb];                            \
    f32x4 R2v = *(const f32x4*)&slab[10 * 64 + jb];                           \
    f32x4 R3v = *(const f32x4*)&slab[11 * 64 + jb];                           \
    f32x4 R4v = *(const f32x4*)&slab[12 * 64 + jb];                           \
    f32x4 C1v = *(const f32x4*)&slab[13 * 64 + jb];                           \
    f32x4 C2v = *(const f32x4*)&slab[14 * 64 + jb];                           \
    f32x4 C3v = *(const f32x4*)&slab[15 * 64 + jb];                           \
    f32x4 C4v = *(const f32x4*)&slab[16 * 64 + jb];                           \
    /* 7 parallel reduces on S_pre */                                         \
    float sa1 = hex_add(fmaf(S0, A1v[0], S1 * A1v[1]) + fmaf(S2, A1v[2], S3 * A1v[3])); \
    float sa2 = hex_add(fmaf(S0, A2v[0], S1 * A2v[1]) + fmaf(S2, A2v[2], S3 * A2v[3])); \
    float sa3 = hex_add(fmaf(S0, A3v[0], S1 * A3v[1]) + fmaf(S2, A3v[2], S3 * A3v[3])); \
    float sa4 = hex_add(fmaf(S0, A4v[0], S1 * A4v[1]) + fmaf(S2, A4v[2], S3 * A4v[3])); \
    float so1 = hex_add(fmaf(S0, R1v[0], S1 * R1v[1]) + fmaf(S2, R1v[2], S3 * R1v[3])); \
    float so2 = hex_add(fmaf(S0, R2v[0], S1 * R2v[1]) + fmaf(S2, R2v[2], S3 * R2v[3])); \
    float so3 = hex_add(fmaf(S0, R3v[0], S1 * R3v[1]) + fmaf(S2, R3v[2], S3 * R3v[3])); \
    if (c == 0) {                                                             \
        out[off + row]             = so1 + oc.x;                              \
        out[off + C_DIM + row]     = so2 + oc.y;                              \
        out[off + 2 * C_DIM + row] = so3 + oc.z;                              \
    }                                                                         \
    /* update: S = S*DD + sum saj*Bj + sum vj*Cj */                           \
    float t0 = fmaf(vq.x, C1v[0], fmaf(vq.y, C2v[0], fmaf(vq.z, C3v[0], vq.w * C4v[0]))); \
    float t1 = fmaf(vq.x, C1v[1], fmaf(vq.y, C2v[1], fmaf(vq.z, C3v[1], vq.w * C4v[1]))); \
    float t2 = fmaf(vq.x, C1v[2], fmaf(vq.y, C2v[2], fmaf(vq.z, C3v[2], vq.w * C4v[2]))); \
    float t3 = fmaf(vq.x, C1v[3], fmaf(vq.y, C2v[3], fmaf(vq.z, C3v[3], vq.w * C4v[3]))); \
    t0 = fmaf(sa1, B1v[0], fmaf(sa2, B2v[0], fmaf(sa3, B3v[0], fmaf(sa4, B4v[0], t0)))); \
    t1 = fmaf(sa1, B1v[1], fmaf(sa2, B2v[1], fmaf(sa3, B3v[1], fmaf(sa4, B4v[1], t1)))); \
    t2 = fmaf(sa1, B1v[2], fmaf(sa2, B2v[2], fmaf(sa3, B3v[2], fmaf(sa4, B4v[2], t2)))); \
    t3 = fmaf(sa1, B1v[3], fmaf(sa2, B2v[3], fmaf(sa3, B3v[3], fmaf(sa4, B4v[3], t3)))); \
    S0 = fmaf(DDv[0], S0, t0);                                                \
    S1 = fmaf(DDv[1], S1, t1);                                                \
    S2 = fmaf(DDv[2], S2, t2);                                                \
    S3 = fmaf(DDv[3], S3, t3);                                                \
    /* out4 on post-update S */                                               \
    float o0 = fmaf(S0, R4v[0], S1 * R4v[1]);                                 \
    float o1 = fmaf(S2, R4v[2], S3 * R4v[3]);                                 \
    float op = hex_add(o0 + o1);                                              \
    if (c == 0) out[off + 3 * C_DIM + row] = op;                              \
    off += 4 * C_DIM;                                                         \
    __builtin_amdgcn_sched_barrier(0);                                        \
} while (0)

#pragma unroll 1
    for (int tq0 = 0; tq0 < NQ; tq0 += 2) {
        SCAN_STEP(0, tq0);
        SCAN_STEP(1, tq0 + 1);
    }
#undef SCAN_STEP
#undef LOADSLOT
}

// ---------------- residual + cast + v_first passthrough ----------------
__global__ __launch_bounds__(64) void resid_k(
    const float* __restrict__ rkv, const float* __restrict__ souts,
    const float* __restrict__ r_k, const float* __restrict__ vfirst,
    __bf16* __restrict__ ob, float* __restrict__ dout) {
    int t = blockIdx.x >> 5;
    int h = blockIdx.x & 31;
    int n = threadIdx.x;
    int cc  = h * HEAD + n;
    int idx = t * C_DIM + cc;
    size_t idx6 = (size_t)t * RKV_N + cc;
    float s = rkv[idx6] * rkv[idx6 + 2048] * r_k[cc];
#pragma unroll
    for (int off = 32; off > 0; off >>= 1) s += __shfl_xor(s, off);
    float ov = souts[idx] + s * rkv[idx6 + 4096];
    ob[idx] = (__bf16)ov;
    dout[BTC + idx] = vfirst[idx];
}

// ---------------- host launcher ----------------
extern "C" void kernel_launch(void* const* d_in, const int* in_sizes, int n_in,
                              void* d_out, int out_size, void* d_ws, size_t ws_size,
                              hipStream_t stream) {
    const float* x      = (const float*)d_in[0];
    const float* vfirst = (const float*)d_in[1];
    const float* amask  = (const float*)d_in[2];
    const float* w0 = (const float*)d_in[3];
    const float* w1 = (const float*)d_in[4];
    const float* w2 = (const float*)d_in[5];
    const float* a0 = (const float*)d_in[6];
    const float* a1 = (const float*)d_in[7];
    const float* a2 = (const float*)d_in[8];
    const float* v0 = (const float*)d_in[9];
    const float* v1 = (const float*)d_in[10];
    const float* v2 = (const float*)d_in[11];
    const float* k_k = (const float*)d_in[12];
    const float* k_a = (const float*)d_in[13];
    const float* r_k = (const float*)d_in[14];
    const float* Wr = (const float*)d_in[15];
    const float* Wk = (const float*)d_in[16];
    const float* Wv = (const float*)d_in[17];
    const float* Wo = (const float*)d_in[18];
    float* dout = (float*)d_out;

    char* wp = (char*)d_ws;
    auto alloc = [&](size_t bytes) -> void* {
        void* p = (void*)wp;
        wp += (bytes + 255) & ~(size_t)255;
        return p;
    };
    __bf16* xb     = (__bf16*)alloc((size_t)BTC * 2);
    __bf16* rkvT   = (__bf16*)alloc((size_t)3 * C_DIM * C_DIM * 2);
    __bf16* WoT    = (__bf16*)alloc((size_t)C_DIM * C_DIM * 2);
    __bf16* lora1T = (__bf16*)alloc((size_t)256 * C_DIM * 2);
    __bf16* w2T = (__bf16*)alloc((size_t)C_DIM * 96 * 2);
    __bf16* a2T = (__bf16*)alloc((size_t)C_DIM * 96 * 2);
    __bf16* v2T = (__bf16*)alloc((size_t)C_DIM * 64 * 2);
    float*  rkv = (float*)alloc((size_t)T_LEN * RKV_N * 4);
    __bf16* hallb = (__bf16*)alloc((size_t)T_LEN * 256 * 2);
    float*  ywb = (float*)alloc((size_t)BTC * 4);
    float*  yab = (float*)alloc((size_t)BTC * 4);
    float*  yvb = (float*)alloc((size_t)BTC * 4);
    float*  pk  = (float*)alloc((size_t)NQ * H_N * REC4 * 4 + 4096);
    float*  souts = (float*)alloc((size_t)BTC * 4);
    __bf16* ob  = (__bf16*)alloc((size_t)BTC * 2);

    // 1) cast x -> bf16
    cast_bf16_k<<<dim3(BTC / 256), 256, 0, stream>>>(x, xb, BTC);

    // 2) ALL weight transposes in one launch
    TransBatch tb;
    tb.s[0] = Wr; tb.d[0] = rkvT;                              tb.R[0] = C_DIM; tb.C[0] = C_DIM;
    tb.s[1] = Wk; tb.d[1] = rkvT + (size_t)C_DIM * C_DIM;      tb.R[1] = C_DIM; tb.C[1] = C_DIM;
    tb.s[2] = Wv; tb.d[2] = rkvT + (size_t)2 * C_DIM * C_DIM;  tb.R[2] = C_DIM; tb.C[2] = C_DIM;
    tb.s[3] = Wo; tb.d[3] = WoT;                               tb.R[3] = C_DIM; tb.C[3] = C_DIM;
    tb.s[4] = w1; tb.d[4] = lora1T;                            tb.R[4] = C_DIM; tb.C[4] = 96;
    tb.s[5] = a1; tb.d[5] = lora1T + (size_t)96 * C_DIM;       tb.R[5] = C_DIM; tb.C[5] = 96;
    tb.s[6] = v1; tb.d[6] = lora1T + (size_t)192 * C_DIM;      tb.R[6] = C_DIM; tb.C[6] = 64;
    tb.s[7] = w2; tb.d[7] = w2T;                               tb.R[7] = 96;    tb.C[7] = C_DIM;
    tb.s[8] = a2; tb.d[8] = a2T;                               tb.R[8] = 96;    tb.C[8] = C_DIM;
    tb.s[9] = v2; tb.d[9] = v2T;                               tb.R[9] = 64;    tb.C[9] = C_DIM;
    transpose_batch_k<<<dim3(64, 64, 10), dim3(32, 8), 0, stream>>>(tb);

    // 3) fused big GEMM: rkv = xb @ [Wr|Wk|Wv]  (128x128 tiles)
    gemm_lds_128x128<<<dim3(8, 48), 256, 0, stream>>>(xb, rkvT, rkv, T_LEN, RKV_N, C_DIM);

    // 4) fused LoRA first stage + activation epilogue: hallb = act(xb @ [w1|a1|v1])
    gemm_lora1_k<<<dim3(64, 16), 64, 0, stream>>>(xb, lora1T, hallb, T_LEN, 256, C_DIM);

    // 5) fused LoRA second stage (grid.z = 3)
    Lora2Cfg lc;
    lc.A[0] = hallb;       lc.BT[0] = w2T; lc.O[0] = ywb; lc.K[0] = 96;
    lc.A[1] = hallb + 96;  lc.BT[1] = a2T; lc.O[1] = yab; lc.K[1] = 96;
    lc.A[2] = hallb + 192; lc.BT[2] = v2T; lc.O[2] = yvb; lc.K[2] = 64;
    gemm_lora2_k<<<dim3(16, 16, 3), 256, 0, stream>>>(lc);

    // 6) prep4: gates + QUAD-step composition packing
    prep4_k<<<dim3(NQ * H_N), 64, 0, stream>>>(rkv, vfirst, ywb, yab, yvb,
                                               pk, w0, a0, v0, k_k, k_a, amask);

    // 7) sequential scan v13: quad-step, packed loads + LDS-bounce redistribution
    scan_k<<<dim3(H_N * 16), 64, 0, stream>>>(pk, souts);

    // 8) residual + cast + v_first passthrough
    resid_k<<<dim3(T_LEN * H_N), 64, 0, stream>>>(rkv, souts, r_k, vfirst, ob, dout);

    // 9) final GEMM: dout[0:BTC] = ob @ Wo
    gemm_lds_64x128<<<dim3(16, 16), 256, 0, stream>>>(ob, WoT, dout, T_LEN, C_DIM, C_DIM);
}